// Round 18
// baseline (289.907 us; speedup 1.0000x reference)
//
#include <hip/hip_runtime.h>

typedef unsigned int uint;
typedef unsigned short ushort;
typedef __attribute__((ext_vector_type(8))) short short8;
typedef __attribute__((ext_vector_type(4))) float f32x4;
typedef __attribute__((ext_vector_type(4))) uint uint4w;

#define T_LEN 32768
#define EMB 300
#define HID 256
#define NCOLS 4096

__device__ __forceinline__ ushort f2bf(float f) {
  uint u = __float_as_uint(f);
  return (ushort)((u + 0x7fffu + ((u >> 16) & 1u)) >> 16);
}
__device__ __forceinline__ float bf2f(ushort u) {
  return __uint_as_float(((uint)u) << 16);
}
// fast transcendentals: v_exp_f32 (2^x) + v_rcp_f32, ~1ulp — avoids IEEE div sequence
__device__ __forceinline__ float fexp2(float x) {
  float r; asm("v_exp_f32 %0, %1" : "=v"(r) : "v"(x)); return r;
}
__device__ __forceinline__ float frcp(float x) {
  float r; asm("v_rcp_f32 %0, %1" : "=v"(r) : "v"(x)); return r;
}
__device__ __forceinline__ float sigm(float x) {
  return frcp(1.f + fexp2(-1.442695041f * x));
}
__device__ __forceinline__ float tanh_(float x) {
  return 2.f * frcp(1.f + fexp2(-2.885390082f * x)) - 1.f;
}

__device__ __forceinline__ void gload_lds16(const void* g, void* l) {
  __builtin_amdgcn_global_load_lds((const __attribute__((address_space(1))) void*)g,
                                   (__attribute__((address_space(3))) void*)l, 16, 0, 0);
}

// ---------------- prep: bf16 conversions + embedding gather ----------------
// Whh3 layout (per-wave contiguous slices):
//   Whh3[d][s(16)][w(8)] = 4 KB block, inner [c(4)][gi(2)][q(2)][ln(16)][e(8)]
//   element = whh_d[gp*512 + gi*256 + w*32 + q*16 + ln][ks*32 + c*8 + e], s = ks*2+gp
__global__ void prep_kernel(const float* __restrict__ emb,
                            const float* __restrict__ wihf, const float* __restrict__ whhf,
                            const float* __restrict__ bihf, const float* __restrict__ bhhf,
                            const float* __restrict__ wihb, const float* __restrict__ whhb,
                            const float* __restrict__ bihb, const float* __restrict__ bhhb,
                            const int* __restrict__ seq,
                            ushort* __restrict__ X, ushort* __restrict__ Wih,
                            ushort* __restrict__ Whh3, float* __restrict__ bias) {
  const int NX = T_LEN * 40;
  const int NWIH = 2048 * 40;
  const int NWHH = 2048 * 32;
  const int NB = 2048;
  const int total = NX + NWIH + NWHH + NB;
  for (int t = blockIdx.x * blockDim.x + threadIdx.x; t < total; t += gridDim.x * blockDim.x) {
    if (t < NX) {
      int r = t / 40, k8 = t % 40, k = k8 * 8;
      int col = r >> 3, j = r & 7;
      int tok = (col == 0) ? j : (col * 8 - 1 + j);
      const float* src = emb + (long)seq[tok] * EMB + k;
      alignas(16) ushort tmp[8];
#pragma unroll
      for (int i = 0; i < 8; ++i) tmp[i] = (k + i < EMB) ? f2bf(src[i]) : (ushort)0;
      *(uint4w*)(X + (long)r * 320 + k) = *(const uint4w*)tmp;
    } else if (t < NX + NWIH) {
      int t2 = t - NX;
      int n = t2 / 40, k8 = t2 % 40, k = k8 * 8;
      const float* src = ((n < 1024) ? wihf : wihb) + (long)(n & 1023) * EMB + k;
      alignas(16) ushort tmp[8];
#pragma unroll
      for (int i = 0; i < 8; ++i) tmp[i] = (k + i < EMB) ? f2bf(src[i]) : (ushort)0;
      *(uint4w*)(Wih + (long)n * 320 + k) = *(const uint4w*)tmp;
    } else if (t < NX + NWIH + NWHH) {
      int t3 = t - NX - NWIH;
      int n = t3 / 32, k8 = t3 % 32;
      int dd = n >> 10, rowg = n & 1023;
      int gp = rowg >> 9, gi = (rowg >> 8) & 1, w5 = (rowg >> 5) & 7;
      int qq = (rowg >> 4) & 1, lnn = rowg & 15;
      int ks = k8 >> 2, cc = k8 & 3, s = ks * 2 + gp;
      const float* src = ((dd == 0) ? whhf : whhb) + (long)rowg * HID + k8 * 8;
      alignas(16) ushort tmp[8];
#pragma unroll
      for (int i = 0; i < 8; ++i) tmp[i] = f2bf(src[i]);
      long didx = (((long)(dd * 16 + s)) * 8 + w5) * 2048 + cc * 512 + gi * 256 + qq * 128 + lnn * 8;
      *(uint4w*)(Whh3 + didx) = *(const uint4w*)tmp;
    } else {
      int n = t - NX - NWIH - NWHH;
      bias[n] = (n < 1024) ? (bihf[n] + bhhf[n]) : (bihb[n - 1024] + bhhb[n - 1024]);
    }
  }
}

// ---------------- K1: xg = X @ Wih^T + bias  (M=32768,K=320,N=2048) ----------------
// 64x256 tile, 4 waves (wave tile 64x64), ~3 blocks/CU (__launch_bounds__(256,3)).
__global__ __launch_bounds__(256, 3) void gemm_xg_kernel(const ushort* __restrict__ X,
                                                         const ushort* __restrict__ Wih,
                                                         const float* __restrict__ bias,
                                                         ushort* __restrict__ xg) {
  __shared__ ushort a_lds[2][64 * 32];   // 2 x 4 KB
  const int tid = threadIdx.x;
  const int lane = tid & 63, w = tid >> 6;     // w in [0,4): wave owns cols w*64..+63
  const int qrow = lane >> 4, ln = lane & 15;
  const int m0 = blockIdx.x * 64, n0 = blockIdx.y * 256;

  auto stage = [&](int buf, int kt) {
    int row = tid >> 2, koff = (tid & 3) * 16;
    const char* src = (const char*)X + (long)(m0 + row) * 640 + kt * 64 + koff;
    void* dst = (char*)&a_lds[buf][0] + w * 1024;  // wave-uniform base
    gload_lds16(src, dst);
  };

  const ushort* wb = Wih + (long)(n0 + w * 64 + ln) * 320 + qrow * 8;
  auto loadB = [&](short8 (&dst)[4], int kt) {
#pragma unroll
    for (int nt = 0; nt < 4; ++nt)
      dst[nt] = *(const short8*)(wb + nt * 16 * 320 + kt * 32);
  };

  const f32x4 fzero = {0.f, 0.f, 0.f, 0.f};
  f32x4 acc[4][4];
#pragma unroll
  for (int i = 0; i < 4; ++i)
#pragma unroll
    for (int jj = 0; jj < 4; ++jj) acc[i][jj] = fzero;

  auto gemmK = [&](short8 (&b)[4], int buf) {
    short8 a[4];
#pragma unroll
    for (int rt = 0; rt < 4; ++rt)
      a[rt] = *(const short8*)&a_lds[buf][(rt * 16 + ln) * 32 + qrow * 8];
#pragma unroll
    for (int rt = 0; rt < 4; ++rt)
#pragma unroll
      for (int nt = 0; nt < 4; ++nt)
        acc[rt][nt] = __builtin_amdgcn_mfma_f32_16x16x32_bf16(a[rt], b[nt], acc[rt][nt], 0, 0, 0);
  };

  short8 bA[4], bB[4];
  stage(0, 0);
  loadB(bA, 0);
#pragma unroll 1
  for (int kt2 = 0; kt2 < 5; ++kt2) {
    const int kt = kt2 * 2;
    __syncthreads();                  // stage(kt) landed (implicit vmcnt drain)
    loadB(bB, kt + 1);
    __builtin_amdgcn_sched_barrier(0);
    if (kt < 9) stage(1, kt + 1);
    __builtin_amdgcn_sched_barrier(0);
    gemmK(bA, 0);
    __syncthreads();                  // stage(kt+1) landed
    if (kt2 < 4) loadB(bA, kt + 2);
    __builtin_amdgcn_sched_barrier(0);
    if (kt + 2 < 10) stage(0, kt + 2);
    __builtin_amdgcn_sched_barrier(0);
    gemmK(bB, 1);
  }

  // epilogue: repack via LDS (16x256 chunk = 8 KB across both a_lds bufs)
  ushort* sbuf = &a_lds[0][0];
  float bv[4];
#pragma unroll
  for (int nt = 0; nt < 4; ++nt) bv[nt] = bias[n0 + w * 64 + nt * 16 + ln];
#pragma unroll
  for (int R = 0; R < 4; ++R) {
    __syncthreads();
#pragma unroll
    for (int nt = 0; nt < 4; ++nt)
#pragma unroll
      for (int r = 0; r < 4; ++r)
        sbuf[(qrow * 4 + r) * 256 + w * 64 + nt * 16 + ln] = f2bf(acc[R][nt][r] + bv[nt]);
    __syncthreads();
    int srow = tid >> 4;              // [0,16)
    int c0 = (tid & 15) * 16;         // 16 ushorts = 32 B per thread
    uint4w v0 = *(uint4w*)&sbuf[srow * 256 + c0];
    uint4w v1 = *(uint4w*)&sbuf[srow * 256 + c0 + 8];
    ushort* gdst = &xg[(long)(m0 + R * 16 + srow) * 2048 + n0 + c0];
    *(uint4w*)gdst = v0;
    *(uint4w*)(gdst + 8) = v1;
  }
}

// ---------------- K2: fused masked LSTM, per-wave staging + operand pipelining ----------------
// xv loads embedded at GEMM phase p==13, right after its vmcnt(0) drain (queue empty):
// they overlap phases 14-15 + stage prefetch + cell barrier, and no later counted wait
// queues behind them (R17 pathology avoided). Cell's implicit wait ~vmcnt(12).
__global__ __launch_bounds__(512) void lstm_kernel(const ushort* __restrict__ xg,
                                                   const ushort* __restrict__ Whh3,
                                                   float* __restrict__ out) {
  __shared__ ushort h_lds[32][264];
  __shared__ alignas(16) char b_lds[8][4][4096];   // [wave][slot][4KB], 128 KB
  const int tid = threadIdx.x;
  const int lane = tid & 63, w = tid >> 6;
  const int qrow = lane >> 4, ln = lane & 15;
  const int bid = blockIdx.x;
  const int d = bid >> 7, cg = bid & 127;

  const char* wsrc = (const char*)Whh3 + (((long)(d * 16) * 8 + w) << 12);  // + s*32768
  char* wdst = &b_lds[w][0][0];

  auto stageB = [&](int s, int slot) {
    const char* src = wsrc + ((long)s << 15) + lane * 16;
    char* dst = wdst + slot * 4096;
#pragma unroll
    for (int q2 = 0; q2 < 4; ++q2) gload_lds16(src + q2 * 1024, dst + q2 * 1024);
  };

  ushort xv[2][2][4][4];   // [rt][q][r][g]
  auto load_xv = [&](int j) {
    const ushort* xgb = xg + (long)(cg * 256 + j) * 2048 + qrow * 65536 + d * 1024 + w * 32 + ln;
#pragma unroll
    for (int rt = 0; rt < 2; ++rt)
#pragma unroll
      for (int q = 0; q < 2; ++q)
#pragma unroll
        for (int r = 0; r < 4; ++r)
#pragma unroll
          for (int g = 0; g < 4; ++g)
            xv[rt][q][r][g] = xgb[(long)rt * 262144 + r * 16384 + g * 256 + q * 16];
  };

  float c_st[2][2][4], h_st[2][2][4];
#pragma unroll
  for (int rt = 0; rt < 2; ++rt)
#pragma unroll
    for (int q = 0; q < 2; ++q)
#pragma unroll
      for (int r = 0; r < 4; ++r) { c_st[rt][q][r] = 0.f; h_st[rt][q][r] = 0.f; }

  const f32x4 fzero = {0.f, 0.f, 0.f, 0.f};

#pragma unroll 1
  for (int it = 0; it < 8; ++it) {
    const int j = d ? (7 - it) : it;
    // step-top barrier: h_lds from previous cell visible
    asm volatile("s_waitcnt lgkmcnt(0)" ::: "memory");
    __builtin_amdgcn_s_barrier();
    asm volatile("" ::: "memory");

    f32x4 acc[4][2][2];
#pragma unroll
    for (int g = 0; g < 4; ++g)
#pragma unroll
      for (int q = 0; q < 2; ++q)
#pragma unroll
        for (int rt = 0; rt < 2; ++rt) acc[g][q][rt] = fzero;

    if (it > 0) {  // h==0 at it==0, skip GEMM
      asm volatile("s_waitcnt vmcnt(4)" ::: "memory");  // slices 0,1 landed
      __builtin_amdgcn_sched_barrier(0);
      short8 bbuf[2][4], abuf[2][2];
      {  // bootstrap: slice-0 B frags + ks0 A frags
        const char* bb = wdst + qrow * 1024;
#pragma unroll
        for (int gi = 0; gi < 2; ++gi)
#pragma unroll
          for (int q = 0; q < 2; ++q)
            bbuf[0][gi * 2 + q] = *(const short8*)(bb + gi * 512 + q * 256 + ln * 16);
        abuf[0][0] = *(const short8*)&h_lds[ln][qrow * 8];
        abuf[0][1] = *(const short8*)&h_lds[16 + ln][qrow * 8];
      }
#pragma unroll
      for (int p = 0; p < 16; ++p) {
        const int ks = p >> 1, gp = p & 1;
        if (p < 15) {
          const char* bb = wdst + ((p + 1) & 3) * 4096 + qrow * 1024;
#pragma unroll
          for (int gi = 0; gi < 2; ++gi)
#pragma unroll
            for (int q = 0; q < 2; ++q)
              bbuf[(p + 1) & 1][gi * 2 + q] = *(const short8*)(bb + gi * 512 + q * 256 + ln * 16);
        }
        if (gp == 1 && ks < 7) {
          abuf[(ks + 1) & 1][0] = *(const short8*)&h_lds[ln][(ks + 1) * 32 + qrow * 8];
          abuf[(ks + 1) & 1][1] = *(const short8*)&h_lds[16 + ln][(ks + 1) * 32 + qrow * 8];
        }
        if (p <= 12) stageB(p + 3, (p + 3) & 3);
        if (p == 15)                 { asm volatile("s_waitcnt lgkmcnt(0)" ::: "memory"); }
        else if (gp == 1 && ks < 7)  { asm volatile("s_waitcnt lgkmcnt(6)" ::: "memory"); }
        else                         { asm volatile("s_waitcnt lgkmcnt(4)" ::: "memory"); }
        __builtin_amdgcn_sched_barrier(0);
        short8 a0 = abuf[ks & 1][0], a1 = abuf[ks & 1][1];
#pragma unroll
        for (int gi = 0; gi < 2; ++gi)
#pragma unroll
          for (int q = 0; q < 2; ++q) {
            short8 b = bbuf[p & 1][gi * 2 + q];
            const int g = gp * 2 + gi;
            acc[g][q][0] = __builtin_amdgcn_mfma_f32_16x16x32_bf16(a0, b, acc[g][q][0], 0, 0, 0);
            acc[g][q][1] = __builtin_amdgcn_mfma_f32_16x16x32_bf16(a1, b, acc[g][q][1], 0, 0, 0);
          }
        // tail fix: slice 15 staged at p=12 must land before its prefetch at p=14
        if (p <= 12)      { asm volatile("s_waitcnt vmcnt(4)" ::: "memory"); }
        else if (p == 13) { asm volatile("s_waitcnt vmcnt(0)" ::: "memory"); }
        __builtin_amdgcn_sched_barrier(0);
        // queue-empty slot: issue this step's xv loads; they hide under p=14,15 + cell barrier
        if (p == 13) { load_xv(j); __builtin_amdgcn_sched_barrier(0); }
      }
    } else {
      load_xv(j);   // it==0: no GEMM; loads hide under stage prefetch + cell barrier
      __builtin_amdgcn_sched_barrier(0);
    }

    // prefetch next step's first 3 slices (lands during cell phase)
    if (it < 7) { stageB(0, 0); stageB(1, 1); stageB(2, 2); }
    __builtin_amdgcn_sched_barrier(0);

    // GEMM h-reads done before cell overwrites h_lds
    asm volatile("s_waitcnt lgkmcnt(0)" ::: "memory");
    __builtin_amdgcn_s_barrier();
    asm volatile("" ::: "memory");

    const bool mstep = d ? (it == 0) : (it == 7);
#pragma unroll
    for (int rt = 0; rt < 2; ++rt)
#pragma unroll
      for (int q = 0; q < 2; ++q)
#pragma unroll
        for (int r = 0; r < 4; ++r) {
          int cc = rt * 16 + qrow * 4 + r;
          int hid = w * 32 + q * 16 + ln;
          float pi = acc[0][q][rt][r] + bf2f(xv[rt][q][r][0]);
          float pf = acc[1][q][rt][r] + bf2f(xv[rt][q][r][1]);
          float pg = acc[2][q][rt][r] + bf2f(xv[rt][q][r][2]);
          float po = acc[3][q][rt][r] + bf2f(xv[rt][q][r][3]);
          float cn = sigm(pf) * c_st[rt][q][r] + sigm(pi) * tanh_(pg);
          float hn = sigm(po) * tanh_(cn);
          bool skip = mstep && (cg == 0) && (cc == 0);
          if (!skip) { c_st[rt][q][r] = cn; h_st[rt][q][r] = hn; }
          h_lds[cc][hid] = f2bf(h_st[rt][q][r]);
        }
  }

#pragma unroll
  for (int rt = 0; rt < 2; ++rt)
#pragma unroll
    for (int q = 0; q < 2; ++q)
#pragma unroll
      for (int r = 0; r < 4; ++r) {
        int cc = rt * 16 + qrow * 4 + r;
        int hid = w * 32 + q * 16 + ln;
        out[(long)(cg * 32 + cc) * 512 + d * 256 + hid] = h_st[rt][q][r];
      }
}

extern "C" void kernel_launch(void* const* d_in, const int* in_sizes, int n_in,
                              void* d_out, int out_size, void* d_ws, size_t ws_size,
                              hipStream_t stream) {
  const float* emb  = (const float*)d_in[0];
  const float* wihf = (const float*)d_in[1];
  const float* whhf = (const float*)d_in[2];
  const float* bihf = (const float*)d_in[3];
  const float* bhhf = (const float*)d_in[4];
  const float* wihb = (const float*)d_in[5];
  const float* whhb = (const float*)d_in[6];
  const float* bihb = (const float*)d_in[7];
  const float* bhhb = (const float*)d_in[8];
  const int*   seq  = (const int*)d_in[9];
  float* out = (float*)d_out;

  char* ws = (char*)d_ws;
  // ws layout (bytes): xg 134217728 | X 20971520 | Wih 1310720 | Whh3 1048576 | bias 8192
  ushort* xg   = (ushort*)(ws);
  ushort* X    = (ushort*)(ws + 134217728);
  ushort* Wih  = (ushort*)(ws + 155189248);
  ushort* Whh3 = (ushort*)(ws + 156499968);
  float*  bias = (float*)(ws + 157548544);

  prep_kernel<<<dim3(1024), dim3(256), 0, stream>>>(emb, wihf, whhf, bihf, bhhf,
                                                    wihb, whhb, bihb, bhhb, seq,
                                                    X, Wih, Whh3, bias);
  gemm_xg_kernel<<<dim3(512, 8), dim3(256), 0, stream>>>(X, Wih, bias, xg);
  lstm_kernel<<<dim3(256), dim3(512), 0, stream>>>(xg, Whh3, out);
}

// Round 19
// 237.101 us; speedup vs baseline: 1.2227x; 1.2227x over previous
//
#include <hip/hip_runtime.h>

typedef unsigned int uint;
typedef unsigned short ushort;
typedef __attribute__((ext_vector_type(8))) short short8;
typedef __attribute__((ext_vector_type(4))) float f32x4;
typedef __attribute__((ext_vector_type(4))) uint uint4w;

#define T_LEN 32768
#define EMB 300
#define HID 256
#define NCOLS 4096

__device__ __forceinline__ ushort f2bf(float f) {
  uint u = __float_as_uint(f);
  return (ushort)((u + 0x7fffu + ((u >> 16) & 1u)) >> 16);
}
__device__ __forceinline__ float bf2f(ushort u) {
  return __uint_as_float(((uint)u) << 16);
}
// fast transcendentals: v_exp_f32 (2^x) + v_rcp_f32, ~1ulp — avoids IEEE div sequence
__device__ __forceinline__ float fexp2(float x) {
  float r; asm("v_exp_f32 %0, %1" : "=v"(r) : "v"(x)); return r;
}
__device__ __forceinline__ float frcp(float x) {
  float r; asm("v_rcp_f32 %0, %1" : "=v"(r) : "v"(x)); return r;
}
__device__ __forceinline__ float sigm(float x) {
  return frcp(1.f + fexp2(-1.442695041f * x));
}
__device__ __forceinline__ float tanh_(float x) {
  return 2.f * frcp(1.f + fexp2(-2.885390082f * x)) - 1.f;
}

__device__ __forceinline__ void gload_lds16(const void* g, void* l) {
  __builtin_amdgcn_global_load_lds((const __attribute__((address_space(1))) void*)g,
                                   (__attribute__((address_space(3))) void*)l, 16, 0, 0);
}

// ---------------- prep: bf16 conversions + embedding gather ----------------
// Whh3 layout (per-wave contiguous slices):
//   Whh3[d][s(16)][w(8)] = 4 KB block, inner [c(4)][gi(2)][q(2)][ln(16)][e(8)]
//   element = whh_d[gp*512 + gi*256 + w*32 + q*16 + ln][ks*32 + c*8 + e], s = ks*2+gp
__global__ void prep_kernel(const float* __restrict__ emb,
                            const float* __restrict__ wihf, const float* __restrict__ whhf,
                            const float* __restrict__ bihf, const float* __restrict__ bhhf,
                            const float* __restrict__ wihb, const float* __restrict__ whhb,
                            const float* __restrict__ bihb, const float* __restrict__ bhhb,
                            const int* __restrict__ seq,
                            ushort* __restrict__ X, ushort* __restrict__ Wih,
                            ushort* __restrict__ Whh3, float* __restrict__ bias) {
  const int NX = T_LEN * 40;
  const int NWIH = 2048 * 40;
  const int NWHH = 2048 * 32;
  const int NB = 2048;
  const int total = NX + NWIH + NWHH + NB;
  for (int t = blockIdx.x * blockDim.x + threadIdx.x; t < total; t += gridDim.x * blockDim.x) {
    if (t < NX) {
      int r = t / 40, k8 = t % 40, k = k8 * 8;
      int col = r >> 3, j = r & 7;
      int tok = (col == 0) ? j : (col * 8 - 1 + j);
      const float* src = emb + (long)seq[tok] * EMB + k;
      alignas(16) ushort tmp[8];
#pragma unroll
      for (int i = 0; i < 8; ++i) tmp[i] = (k + i < EMB) ? f2bf(src[i]) : (ushort)0;
      *(uint4w*)(X + (long)r * 320 + k) = *(const uint4w*)tmp;
    } else if (t < NX + NWIH) {
      int t2 = t - NX;
      int n = t2 / 40, k8 = t2 % 40, k = k8 * 8;
      const float* src = ((n < 1024) ? wihf : wihb) + (long)(n & 1023) * EMB + k;
      alignas(16) ushort tmp[8];
#pragma unroll
      for (int i = 0; i < 8; ++i) tmp[i] = (k + i < EMB) ? f2bf(src[i]) : (ushort)0;
      *(uint4w*)(Wih + (long)n * 320 + k) = *(const uint4w*)tmp;
    } else if (t < NX + NWIH + NWHH) {
      int t3 = t - NX - NWIH;
      int n = t3 / 32, k8 = t3 % 32;
      int dd = n >> 10, rowg = n & 1023;
      int gp = rowg >> 9, gi = (rowg >> 8) & 1, w5 = (rowg >> 5) & 7;
      int qq = (rowg >> 4) & 1, lnn = rowg & 15;
      int ks = k8 >> 2, cc = k8 & 3, s = ks * 2 + gp;
      const float* src = ((dd == 0) ? whhf : whhb) + (long)rowg * HID + k8 * 8;
      alignas(16) ushort tmp[8];
#pragma unroll
      for (int i = 0; i < 8; ++i) tmp[i] = f2bf(src[i]);
      long didx = (((long)(dd * 16 + s)) * 8 + w5) * 2048 + cc * 512 + gi * 256 + qq * 128 + lnn * 8;
      *(uint4w*)(Whh3 + didx) = *(const uint4w*)tmp;
    } else {
      int n = t - NX - NWIH - NWHH;
      bias[n] = (n < 1024) ? (bihf[n] + bhhf[n]) : (bihb[n - 1024] + bhhb[n - 1024]);
    }
  }
}

// ---------------- K1: xg = X @ Wih^T + bias  (M=32768,K=320,N=2048) ----------------
// 64x256 tile, 4 waves (wave tile 64x64), ~3 blocks/CU (__launch_bounds__(256,3)).
__global__ __launch_bounds__(256, 3) void gemm_xg_kernel(const ushort* __restrict__ X,
                                                         const ushort* __restrict__ Wih,
                                                         const float* __restrict__ bias,
                                                         ushort* __restrict__ xg) {
  __shared__ ushort a_lds[2][64 * 32];   // 2 x 4 KB
  const int tid = threadIdx.x;
  const int lane = tid & 63, w = tid >> 6;     // w in [0,4): wave owns cols w*64..+63
  const int qrow = lane >> 4, ln = lane & 15;
  const int m0 = blockIdx.x * 64, n0 = blockIdx.y * 256;

  auto stage = [&](int buf, int kt) {
    int row = tid >> 2, koff = (tid & 3) * 16;
    const char* src = (const char*)X + (long)(m0 + row) * 640 + kt * 64 + koff;
    void* dst = (char*)&a_lds[buf][0] + w * 1024;  // wave-uniform base
    gload_lds16(src, dst);
  };

  const ushort* wb = Wih + (long)(n0 + w * 64 + ln) * 320 + qrow * 8;
  auto loadB = [&](short8 (&dst)[4], int kt) {
#pragma unroll
    for (int nt = 0; nt < 4; ++nt)
      dst[nt] = *(const short8*)(wb + nt * 16 * 320 + kt * 32);
  };

  const f32x4 fzero = {0.f, 0.f, 0.f, 0.f};
  f32x4 acc[4][4];
#pragma unroll
  for (int i = 0; i < 4; ++i)
#pragma unroll
    for (int jj = 0; jj < 4; ++jj) acc[i][jj] = fzero;

  auto gemmK = [&](short8 (&b)[4], int buf) {
    short8 a[4];
#pragma unroll
    for (int rt = 0; rt < 4; ++rt)
      a[rt] = *(const short8*)&a_lds[buf][(rt * 16 + ln) * 32 + qrow * 8];
#pragma unroll
    for (int rt = 0; rt < 4; ++rt)
#pragma unroll
      for (int nt = 0; nt < 4; ++nt)
        acc[rt][nt] = __builtin_amdgcn_mfma_f32_16x16x32_bf16(a[rt], b[nt], acc[rt][nt], 0, 0, 0);
  };

  short8 bA[4], bB[4];
  stage(0, 0);
  loadB(bA, 0);
#pragma unroll 1
  for (int kt2 = 0; kt2 < 5; ++kt2) {
    const int kt = kt2 * 2;
    __syncthreads();                  // stage(kt) landed (implicit vmcnt drain)
    loadB(bB, kt + 1);
    __builtin_amdgcn_sched_barrier(0);
    if (kt < 9) stage(1, kt + 1);
    __builtin_amdgcn_sched_barrier(0);
    gemmK(bA, 0);
    __syncthreads();                  // stage(kt+1) landed
    if (kt2 < 4) loadB(bA, kt + 2);
    __builtin_amdgcn_sched_barrier(0);
    if (kt + 2 < 10) stage(0, kt + 2);
    __builtin_amdgcn_sched_barrier(0);
    gemmK(bB, 1);
  }

  // epilogue: repack via LDS (16x256 chunk = 8 KB across both a_lds bufs)
  ushort* sbuf = &a_lds[0][0];
  float bv[4];
#pragma unroll
  for (int nt = 0; nt < 4; ++nt) bv[nt] = bias[n0 + w * 64 + nt * 16 + ln];
#pragma unroll
  for (int R = 0; R < 4; ++R) {
    __syncthreads();
#pragma unroll
    for (int nt = 0; nt < 4; ++nt)
#pragma unroll
      for (int r = 0; r < 4; ++r)
        sbuf[(qrow * 4 + r) * 256 + w * 64 + nt * 16 + ln] = f2bf(acc[R][nt][r] + bv[nt]);
    __syncthreads();
    int srow = tid >> 4;              // [0,16)
    int c0 = (tid & 15) * 16;         // 16 ushorts = 32 B per thread
    uint4w v0 = *(uint4w*)&sbuf[srow * 256 + c0];
    uint4w v1 = *(uint4w*)&sbuf[srow * 256 + c0 + 8];
    ushort* gdst = &xg[(long)(m0 + R * 16 + srow) * 2048 + n0 + c0];
    *(uint4w*)gdst = v0;
    *(uint4w*)(gdst + 8) = v1;
  }
}

// ---------------- K2: fused masked LSTM, per-wave staging + operand pipelining ----------------
// R16 configuration (empirical optimum): xv loaded serially between the stage prefetch
// and the cell barrier. Two attempts to prefetch xv earlier (post-cell R17, in-GEMM R18)
// both regressed — in-order vmem retirement makes later counted waits drain them.
__global__ __launch_bounds__(512) void lstm_kernel(const ushort* __restrict__ xg,
                                                   const ushort* __restrict__ Whh3,
                                                   float* __restrict__ out) {
  __shared__ ushort h_lds[32][264];
  __shared__ alignas(16) char b_lds[8][4][4096];   // [wave][slot][4KB], 128 KB
  const int tid = threadIdx.x;
  const int lane = tid & 63, w = tid >> 6;
  const int qrow = lane >> 4, ln = lane & 15;
  const int bid = blockIdx.x;
  const int d = bid >> 7, cg = bid & 127;

  const char* wsrc = (const char*)Whh3 + (((long)(d * 16) * 8 + w) << 12);  // + s*32768
  char* wdst = &b_lds[w][0][0];

  auto stageB = [&](int s, int slot) {
    const char* src = wsrc + ((long)s << 15) + lane * 16;
    char* dst = wdst + slot * 4096;
#pragma unroll
    for (int q2 = 0; q2 < 4; ++q2) gload_lds16(src + q2 * 1024, dst + q2 * 1024);
  };

  float c_st[2][2][4], h_st[2][2][4];
#pragma unroll
  for (int rt = 0; rt < 2; ++rt)
#pragma unroll
    for (int q = 0; q < 2; ++q)
#pragma unroll
      for (int r = 0; r < 4; ++r) { c_st[rt][q][r] = 0.f; h_st[rt][q][r] = 0.f; }

  const f32x4 fzero = {0.f, 0.f, 0.f, 0.f};

#pragma unroll 1
  for (int it = 0; it < 8; ++it) {
    const int j = d ? (7 - it) : it;
    // step-top barrier: h_lds from previous cell visible
    asm volatile("s_waitcnt lgkmcnt(0)" ::: "memory");
    __builtin_amdgcn_s_barrier();
    asm volatile("" ::: "memory");

    f32x4 acc[4][2][2];
#pragma unroll
    for (int g = 0; g < 4; ++g)
#pragma unroll
      for (int q = 0; q < 2; ++q)
#pragma unroll
        for (int rt = 0; rt < 2; ++rt) acc[g][q][rt] = fzero;

    if (it > 0) {  // h==0 at it==0, skip GEMM
      asm volatile("s_waitcnt vmcnt(4)" ::: "memory");  // slices 0,1 landed
      __builtin_amdgcn_sched_barrier(0);
      short8 bbuf[2][4], abuf[2][2];
      {  // bootstrap: slice-0 B frags + ks0 A frags
        const char* bb = wdst + qrow * 1024;
#pragma unroll
        for (int gi = 0; gi < 2; ++gi)
#pragma unroll
          for (int q = 0; q < 2; ++q)
            bbuf[0][gi * 2 + q] = *(const short8*)(bb + gi * 512 + q * 256 + ln * 16);
        abuf[0][0] = *(const short8*)&h_lds[ln][qrow * 8];
        abuf[0][1] = *(const short8*)&h_lds[16 + ln][qrow * 8];
      }
#pragma unroll
      for (int p = 0; p < 16; ++p) {
        const int ks = p >> 1, gp = p & 1;
        if (p < 15) {
          const char* bb = wdst + ((p + 1) & 3) * 4096 + qrow * 1024;
#pragma unroll
          for (int gi = 0; gi < 2; ++gi)
#pragma unroll
            for (int q = 0; q < 2; ++q)
              bbuf[(p + 1) & 1][gi * 2 + q] = *(const short8*)(bb + gi * 512 + q * 256 + ln * 16);
        }
        if (gp == 1 && ks < 7) {
          abuf[(ks + 1) & 1][0] = *(const short8*)&h_lds[ln][(ks + 1) * 32 + qrow * 8];
          abuf[(ks + 1) & 1][1] = *(const short8*)&h_lds[16 + ln][(ks + 1) * 32 + qrow * 8];
        }
        if (p <= 12) stageB(p + 3, (p + 3) & 3);
        if (p == 15)                 { asm volatile("s_waitcnt lgkmcnt(0)" ::: "memory"); }
        else if (gp == 1 && ks < 7)  { asm volatile("s_waitcnt lgkmcnt(6)" ::: "memory"); }
        else                         { asm volatile("s_waitcnt lgkmcnt(4)" ::: "memory"); }
        __builtin_amdgcn_sched_barrier(0);
        short8 a0 = abuf[ks & 1][0], a1 = abuf[ks & 1][1];
#pragma unroll
        for (int gi = 0; gi < 2; ++gi)
#pragma unroll
          for (int q = 0; q < 2; ++q) {
            short8 b = bbuf[p & 1][gi * 2 + q];
            const int g = gp * 2 + gi;
            acc[g][q][0] = __builtin_amdgcn_mfma_f32_16x16x32_bf16(a0, b, acc[g][q][0], 0, 0, 0);
            acc[g][q][1] = __builtin_amdgcn_mfma_f32_16x16x32_bf16(a1, b, acc[g][q][1], 0, 0, 0);
          }
        // tail fix: slice 15 staged at p=12 must land before its prefetch at p=14
        if (p <= 12)      { asm volatile("s_waitcnt vmcnt(4)" ::: "memory"); }
        else if (p == 13) { asm volatile("s_waitcnt vmcnt(0)" ::: "memory"); }
        __builtin_amdgcn_sched_barrier(0);
      }
    }

    // prefetch next step's first 3 slices (lands during cell phase)
    if (it < 7) { stageB(0, 0); stageB(1, 1); stageB(2, 2); }
    __builtin_amdgcn_sched_barrier(0);

    // per-lane xg loads for this step
    const ushort* xgb = xg + (long)(cg * 256 + j) * 2048 + qrow * 65536 + d * 1024 + w * 32 + ln;
    ushort xv[2][2][4][4];
#pragma unroll
    for (int rt = 0; rt < 2; ++rt)
#pragma unroll
      for (int q = 0; q < 2; ++q)
#pragma unroll
        for (int r = 0; r < 4; ++r)
#pragma unroll
          for (int g = 0; g < 4; ++g)
            xv[rt][q][r][g] = xgb[(long)rt * 262144 + r * 16384 + g * 256 + q * 16];

    // GEMM h-reads done before cell overwrites h_lds
    asm volatile("s_waitcnt lgkmcnt(0)" ::: "memory");
    __builtin_amdgcn_s_barrier();
    asm volatile("" ::: "memory");

    const bool mstep = d ? (it == 0) : (it == 7);
#pragma unroll
    for (int rt = 0; rt < 2; ++rt)
#pragma unroll
      for (int q = 0; q < 2; ++q)
#pragma unroll
        for (int r = 0; r < 4; ++r) {
          int cc = rt * 16 + qrow * 4 + r;
          int hid = w * 32 + q * 16 + ln;
          float pi = acc[0][q][rt][r] + bf2f(xv[rt][q][r][0]);
          float pf = acc[1][q][rt][r] + bf2f(xv[rt][q][r][1]);
          float pg = acc[2][q][rt][r] + bf2f(xv[rt][q][r][2]);
          float po = acc[3][q][rt][r] + bf2f(xv[rt][q][r][3]);
          float cn = sigm(pf) * c_st[rt][q][r] + sigm(pi) * tanh_(pg);
          float hn = sigm(po) * tanh_(cn);
          bool skip = mstep && (cg == 0) && (cc == 0);
          if (!skip) { c_st[rt][q][r] = cn; h_st[rt][q][r] = hn; }
          h_lds[cc][hid] = f2bf(h_st[rt][q][r]);
        }
  }

#pragma unroll
  for (int rt = 0; rt < 2; ++rt)
#pragma unroll
    for (int q = 0; q < 2; ++q)
#pragma unroll
      for (int r = 0; r < 4; ++r) {
        int cc = rt * 16 + qrow * 4 + r;
        int hid = w * 32 + q * 16 + ln;
        out[(long)(cg * 32 + cc) * 512 + d * 256 + hid] = h_st[rt][q][r];
      }
}

extern "C" void kernel_launch(void* const* d_in, const int* in_sizes, int n_in,
                              void* d_out, int out_size, void* d_ws, size_t ws_size,
                              hipStream_t stream) {
  const float* emb  = (const float*)d_in[0];
  const float* wihf = (const float*)d_in[1];
  const float* whhf = (const float*)d_in[2];
  const float* bihf = (const float*)d_in[3];
  const float* bhhf = (const float*)d_in[4];
  const float* wihb = (const float*)d_in[5];
  const float* whhb = (const float*)d_in[6];
  const float* bihb = (const float*)d_in[7];
  const float* bhhb = (const float*)d_in[8];
  const int*   seq  = (const int*)d_in[9];
  float* out = (float*)d_out;

  char* ws = (char*)d_ws;
  // ws layout (bytes): xg 134217728 | X 20971520 | Wih 1310720 | Whh3 1048576 | bias 8192
  ushort* xg   = (ushort*)(ws);
  ushort* X    = (ushort*)(ws + 134217728);
  ushort* Wih  = (ushort*)(ws + 155189248);
  ushort* Whh3 = (ushort*)(ws + 156499968);
  float*  bias = (float*)(ws + 157548544);

  prep_kernel<<<dim3(1024), dim3(256), 0, stream>>>(emb, wihf, whhf, bihf, bhhf,
                                                    wihb, whhb, bihb, bhhb, seq,
                                                    X, Wih, Whh3, bias);
  gemm_xg_kernel<<<dim3(512, 8), dim3(256), 0, stream>>>(X, Wih, bias, xg);
  lstm_kernel<<<dim3(256), dim3(512), 0, stream>>>(xg, Whh3, out);
}

// Round 20
// 236.815 us; speedup vs baseline: 1.2242x; 1.0012x over previous
//
#include <hip/hip_runtime.h>

typedef unsigned int uint;
typedef unsigned short ushort;
typedef __attribute__((ext_vector_type(8))) short short8;
typedef __attribute__((ext_vector_type(4))) float f32x4;
typedef __attribute__((ext_vector_type(4))) uint uint4w;

#define T_LEN 32768
#define EMB 300
#define HID 256
#define NCOLS 4096

__device__ __forceinline__ ushort f2bf(float f) {
  uint u = __float_as_uint(f);
  return (ushort)((u + 0x7fffu + ((u >> 16) & 1u)) >> 16);
}
__device__ __forceinline__ float bf2f(ushort u) {
  return __uint_as_float(((uint)u) << 16);
}
// fast transcendentals: v_exp_f32 (2^x) + v_rcp_f32, ~1ulp — avoids IEEE div sequence
__device__ __forceinline__ float fexp2(float x) {
  float r; asm("v_exp_f32 %0, %1" : "=v"(r) : "v"(x)); return r;
}
__device__ __forceinline__ float frcp(float x) {
  float r; asm("v_rcp_f32 %0, %1" : "=v"(r) : "v"(x)); return r;
}
__device__ __forceinline__ float sigm(float x) {
  return frcp(1.f + fexp2(-1.442695041f * x));
}
__device__ __forceinline__ float tanh_(float x) {
  return 2.f * frcp(1.f + fexp2(-2.885390082f * x)) - 1.f;
}

__device__ __forceinline__ void gload_lds16(const void* g, void* l) {
  __builtin_amdgcn_global_load_lds((const __attribute__((address_space(1))) void*)g,
                                   (__attribute__((address_space(3))) void*)l, 16, 0, 0);
}

// ---------------- prep: bf16 conversions + embedding gather ----------------
// Whh3 layout (per-wave contiguous slices):
//   Whh3[d][s(16)][w(8)] = 4 KB block, inner [c(4)][gi(2)][q(2)][ln(16)][e(8)]
//   element = whh_d[gp*512 + gi*256 + w*32 + q*16 + ln][ks*32 + c*8 + e], s = ks*2+gp
__global__ void prep_kernel(const float* __restrict__ emb,
                            const float* __restrict__ wihf, const float* __restrict__ whhf,
                            const float* __restrict__ bihf, const float* __restrict__ bhhf,
                            const float* __restrict__ wihb, const float* __restrict__ whhb,
                            const float* __restrict__ bihb, const float* __restrict__ bhhb,
                            const int* __restrict__ seq,
                            ushort* __restrict__ X, ushort* __restrict__ Wih,
                            ushort* __restrict__ Whh3, float* __restrict__ bias) {
  const int NX = T_LEN * 40;
  const int NWIH = 2048 * 40;
  const int NWHH = 2048 * 32;
  const int NB = 2048;
  const int total = NX + NWIH + NWHH + NB;
  for (int t = blockIdx.x * blockDim.x + threadIdx.x; t < total; t += gridDim.x * blockDim.x) {
    if (t < NX) {
      int r = t / 40, k8 = t % 40, k = k8 * 8;
      int col = r >> 3, j = r & 7;
      int tok = (col == 0) ? j : (col * 8 - 1 + j);
      const float* src = emb + (long)seq[tok] * EMB + k;
      alignas(16) ushort tmp[8];
#pragma unroll
      for (int i = 0; i < 8; ++i) tmp[i] = (k + i < EMB) ? f2bf(src[i]) : (ushort)0;
      *(uint4w*)(X + (long)r * 320 + k) = *(const uint4w*)tmp;
    } else if (t < NX + NWIH) {
      int t2 = t - NX;
      int n = t2 / 40, k8 = t2 % 40, k = k8 * 8;
      const float* src = ((n < 1024) ? wihf : wihb) + (long)(n & 1023) * EMB + k;
      alignas(16) ushort tmp[8];
#pragma unroll
      for (int i = 0; i < 8; ++i) tmp[i] = (k + i < EMB) ? f2bf(src[i]) : (ushort)0;
      *(uint4w*)(Wih + (long)n * 320 + k) = *(const uint4w*)tmp;
    } else if (t < NX + NWIH + NWHH) {
      int t3 = t - NX - NWIH;
      int n = t3 / 32, k8 = t3 % 32;
      int dd = n >> 10, rowg = n & 1023;
      int gp = rowg >> 9, gi = (rowg >> 8) & 1, w5 = (rowg >> 5) & 7;
      int qq = (rowg >> 4) & 1, lnn = rowg & 15;
      int ks = k8 >> 2, cc = k8 & 3, s = ks * 2 + gp;
      const float* src = ((dd == 0) ? whhf : whhb) + (long)rowg * HID + k8 * 8;
      alignas(16) ushort tmp[8];
#pragma unroll
      for (int i = 0; i < 8; ++i) tmp[i] = f2bf(src[i]);
      long didx = (((long)(dd * 16 + s)) * 8 + w5) * 2048 + cc * 512 + gi * 256 + qq * 128 + lnn * 8;
      *(uint4w*)(Whh3 + didx) = *(const uint4w*)tmp;
    } else {
      int n = t - NX - NWIH - NWHH;
      bias[n] = (n < 1024) ? (bihf[n] + bhhf[n]) : (bihb[n - 1024] + bhhb[n - 1024]);
    }
  }
}

// ---------------- K1: xg = X @ Wih^T + bias  (M=32768,K=320,N=2048) ----------------
// 64x256 tile, 4 waves, ~3 blocks/CU. 2 k-steps per barrier phase with a 4-buffer
// A-ring: 5 full-drain barriers instead of 10. Queue discipline: loadB issued BEFORE
// the stage pair (B waits never queue behind staging; R16/R17 lesson).
__global__ __launch_bounds__(256, 3) void gemm_xg_kernel(const ushort* __restrict__ X,
                                                         const ushort* __restrict__ Wih,
                                                         const float* __restrict__ bias,
                                                         ushort* __restrict__ xg) {
  __shared__ ushort a_lds[4][64 * 32];   // 4 x 4 KB ring
  const int tid = threadIdx.x;
  const int lane = tid & 63, w = tid >> 6;     // w in [0,4): wave owns cols w*64..+63
  const int qrow = lane >> 4, ln = lane & 15;
  const int m0 = blockIdx.x * 64, n0 = blockIdx.y * 256;

  auto stage = [&](int buf, int kt) {
    int row = tid >> 2, koff = (tid & 3) * 16;
    const char* src = (const char*)X + (long)(m0 + row) * 640 + kt * 64 + koff;
    void* dst = (char*)&a_lds[buf][0] + w * 1024;  // wave-uniform base
    gload_lds16(src, dst);
  };

  const ushort* wb = Wih + (long)(n0 + w * 64 + ln) * 320 + qrow * 8;
  auto loadB = [&](short8 (&dst)[4], int kt) {
#pragma unroll
    for (int nt = 0; nt < 4; ++nt)
      dst[nt] = *(const short8*)(wb + nt * 16 * 320 + kt * 32);
  };

  const f32x4 fzero = {0.f, 0.f, 0.f, 0.f};
  f32x4 acc[4][4];
#pragma unroll
  for (int i = 0; i < 4; ++i)
#pragma unroll
    for (int jj = 0; jj < 4; ++jj) acc[i][jj] = fzero;

  auto gemmK = [&](short8 (&b)[4], int buf) {
    short8 a[4];
#pragma unroll
    for (int rt = 0; rt < 4; ++rt)
      a[rt] = *(const short8*)&a_lds[buf][(rt * 16 + ln) * 32 + qrow * 8];
#pragma unroll
    for (int rt = 0; rt < 4; ++rt)
#pragma unroll
      for (int nt = 0; nt < 4; ++nt)
        acc[rt][nt] = __builtin_amdgcn_mfma_f32_16x16x32_bf16(a[rt], b[nt], acc[rt][nt], 0, 0, 0);
  };

  short8 bA[4], bB[4];
  stage(0, 0);
  stage(1, 1);
  loadB(bA, 0);
#pragma unroll 1
  for (int p = 0; p < 5; ++p) {        // phase p covers kts 2p, 2p+1 in bufs (2p)&3,(2p+1)&3
    const int kt = p * 2;
    __syncthreads();                   // full drain: this phase's bufs landed; prev reads done
    loadB(bB, kt + 1);                 // B first in queue (retires without staging waits)
    __builtin_amdgcn_sched_barrier(0);
    if (p < 4) { stage((kt + 2) & 3, kt + 2); stage((kt + 3) & 3, kt + 3); }
    __builtin_amdgcn_sched_barrier(0);
    gemmK(bA, kt & 3);
    if (p < 4) loadB(bA, kt + 2);      // consumed next phase (post-barrier drain)
    __builtin_amdgcn_sched_barrier(0);
    gemmK(bB, (kt + 1) & 3);
  }

  // epilogue: repack via LDS (16x256 chunk = 8 KB in a_lds[0..1])
  ushort* sbuf = &a_lds[0][0];
  float bv[4];
#pragma unroll
  for (int nt = 0; nt < 4; ++nt) bv[nt] = bias[n0 + w * 64 + nt * 16 + ln];
#pragma unroll
  for (int R = 0; R < 4; ++R) {
    __syncthreads();
#pragma unroll
    for (int nt = 0; nt < 4; ++nt)
#pragma unroll
      for (int r = 0; r < 4; ++r)
        sbuf[(qrow * 4 + r) * 256 + w * 64 + nt * 16 + ln] = f2bf(acc[R][nt][r] + bv[nt]);
    __syncthreads();
    int srow = tid >> 4;              // [0,16)
    int c0 = (tid & 15) * 16;         // 16 ushorts = 32 B per thread
    uint4w v0 = *(uint4w*)&sbuf[srow * 256 + c0];
    uint4w v1 = *(uint4w*)&sbuf[srow * 256 + c0 + 8];
    ushort* gdst = &xg[(long)(m0 + R * 16 + srow) * 2048 + n0 + c0];
    *(uint4w*)gdst = v0;
    *(uint4w*)(gdst + 8) = v1;
  }
}

// ---------------- K2: fused masked LSTM, per-wave staging + operand pipelining ----------------
// R16 configuration (empirical optimum): xv loaded serially between the stage prefetch
// and the cell barrier. Earlier xv prefetch placements (R17 post-cell, R18 in-GEMM)
// both regressed — in-order vmem retirement makes later counted waits drain them.
__global__ __launch_bounds__(512) void lstm_kernel(const ushort* __restrict__ xg,
                                                   const ushort* __restrict__ Whh3,
                                                   float* __restrict__ out) {
  __shared__ ushort h_lds[32][264];
  __shared__ alignas(16) char b_lds[8][4][4096];   // [wave][slot][4KB], 128 KB
  const int tid = threadIdx.x;
  const int lane = tid & 63, w = tid >> 6;
  const int qrow = lane >> 4, ln = lane & 15;
  const int bid = blockIdx.x;
  const int d = bid >> 7, cg = bid & 127;

  const char* wsrc = (const char*)Whh3 + (((long)(d * 16) * 8 + w) << 12);  // + s*32768
  char* wdst = &b_lds[w][0][0];

  auto stageB = [&](int s, int slot) {
    const char* src = wsrc + ((long)s << 15) + lane * 16;
    char* dst = wdst + slot * 4096;
#pragma unroll
    for (int q2 = 0; q2 < 4; ++q2) gload_lds16(src + q2 * 1024, dst + q2 * 1024);
  };

  float c_st[2][2][4], h_st[2][2][4];
#pragma unroll
  for (int rt = 0; rt < 2; ++rt)
#pragma unroll
    for (int q = 0; q < 2; ++q)
#pragma unroll
      for (int r = 0; r < 4; ++r) { c_st[rt][q][r] = 0.f; h_st[rt][q][r] = 0.f; }

  const f32x4 fzero = {0.f, 0.f, 0.f, 0.f};

#pragma unroll 1
  for (int it = 0; it < 8; ++it) {
    const int j = d ? (7 - it) : it;
    // step-top barrier: h_lds from previous cell visible
    asm volatile("s_waitcnt lgkmcnt(0)" ::: "memory");
    __builtin_amdgcn_s_barrier();
    asm volatile("" ::: "memory");

    f32x4 acc[4][2][2];
#pragma unroll
    for (int g = 0; g < 4; ++g)
#pragma unroll
      for (int q = 0; q < 2; ++q)
#pragma unroll
        for (int rt = 0; rt < 2; ++rt) acc[g][q][rt] = fzero;

    if (it > 0) {  // h==0 at it==0, skip GEMM
      asm volatile("s_waitcnt vmcnt(4)" ::: "memory");  // slices 0,1 landed
      __builtin_amdgcn_sched_barrier(0);
      short8 bbuf[2][4], abuf[2][2];
      {  // bootstrap: slice-0 B frags + ks0 A frags
        const char* bb = wdst + qrow * 1024;
#pragma unroll
        for (int gi = 0; gi < 2; ++gi)
#pragma unroll
          for (int q = 0; q < 2; ++q)
            bbuf[0][gi * 2 + q] = *(const short8*)(bb + gi * 512 + q * 256 + ln * 16);
        abuf[0][0] = *(const short8*)&h_lds[ln][qrow * 8];
        abuf[0][1] = *(const short8*)&h_lds[16 + ln][qrow * 8];
      }
#pragma unroll
      for (int p = 0; p < 16; ++p) {
        const int ks = p >> 1, gp = p & 1;
        if (p < 15) {
          const char* bb = wdst + ((p + 1) & 3) * 4096 + qrow * 1024;
#pragma unroll
          for (int gi = 0; gi < 2; ++gi)
#pragma unroll
            for (int q = 0; q < 2; ++q)
              bbuf[(p + 1) & 1][gi * 2 + q] = *(const short8*)(bb + gi * 512 + q * 256 + ln * 16);
        }
        if (gp == 1 && ks < 7) {
          abuf[(ks + 1) & 1][0] = *(const short8*)&h_lds[ln][(ks + 1) * 32 + qrow * 8];
          abuf[(ks + 1) & 1][1] = *(const short8*)&h_lds[16 + ln][(ks + 1) * 32 + qrow * 8];
        }
        if (p <= 12) stageB(p + 3, (p + 3) & 3);
        if (p == 15)                 { asm volatile("s_waitcnt lgkmcnt(0)" ::: "memory"); }
        else if (gp == 1 && ks < 7)  { asm volatile("s_waitcnt lgkmcnt(6)" ::: "memory"); }
        else                         { asm volatile("s_waitcnt lgkmcnt(4)" ::: "memory"); }
        __builtin_amdgcn_sched_barrier(0);
        short8 a0 = abuf[ks & 1][0], a1 = abuf[ks & 1][1];
#pragma unroll
        for (int gi = 0; gi < 2; ++gi)
#pragma unroll
          for (int q = 0; q < 2; ++q) {
            short8 b = bbuf[p & 1][gi * 2 + q];
            const int g = gp * 2 + gi;
            acc[g][q][0] = __builtin_amdgcn_mfma_f32_16x16x32_bf16(a0, b, acc[g][q][0], 0, 0, 0);
            acc[g][q][1] = __builtin_amdgcn_mfma_f32_16x16x32_bf16(a1, b, acc[g][q][1], 0, 0, 0);
          }
        // tail fix: slice 15 staged at p=12 must land before its prefetch at p=14
        if (p <= 12)      { asm volatile("s_waitcnt vmcnt(4)" ::: "memory"); }
        else if (p == 13) { asm volatile("s_waitcnt vmcnt(0)" ::: "memory"); }
        __builtin_amdgcn_sched_barrier(0);
      }
    }

    // prefetch next step's first 3 slices (lands during cell phase)
    if (it < 7) { stageB(0, 0); stageB(1, 1); stageB(2, 2); }
    __builtin_amdgcn_sched_barrier(0);

    // per-lane xg loads for this step
    const ushort* xgb = xg + (long)(cg * 256 + j) * 2048 + qrow * 65536 + d * 1024 + w * 32 + ln;
    ushort xv[2][2][4][4];
#pragma unroll
    for (int rt = 0; rt < 2; ++rt)
#pragma unroll
      for (int q = 0; q < 2; ++q)
#pragma unroll
        for (int r = 0; r < 4; ++r)
#pragma unroll
          for (int g = 0; g < 4; ++g)
            xv[rt][q][r][g] = xgb[(long)rt * 262144 + r * 16384 + g * 256 + q * 16];

    // GEMM h-reads done before cell overwrites h_lds
    asm volatile("s_waitcnt lgkmcnt(0)" ::: "memory");
    __builtin_amdgcn_s_barrier();
    asm volatile("" ::: "memory");

    const bool mstep = d ? (it == 0) : (it == 7);
#pragma unroll
    for (int rt = 0; rt < 2; ++rt)
#pragma unroll
      for (int q = 0; q < 2; ++q)
#pragma unroll
        for (int r = 0; r < 4; ++r) {
          int cc = rt * 16 + qrow * 4 + r;
          int hid = w * 32 + q * 16 + ln;
          float pi = acc[0][q][rt][r] + bf2f(xv[rt][q][r][0]);
          float pf = acc[1][q][rt][r] + bf2f(xv[rt][q][r][1]);
          float pg = acc[2][q][rt][r] + bf2f(xv[rt][q][r][2]);
          float po = acc[3][q][rt][r] + bf2f(xv[rt][q][r][3]);
          float cn = sigm(pf) * c_st[rt][q][r] + sigm(pi) * tanh_(pg);
          float hn = sigm(po) * tanh_(cn);
          bool skip = mstep && (cg == 0) && (cc == 0);
          if (!skip) { c_st[rt][q][r] = cn; h_st[rt][q][r] = hn; }
          h_lds[cc][hid] = f2bf(h_st[rt][q][r]);
        }
  }

#pragma unroll
  for (int rt = 0; rt < 2; ++rt)
#pragma unroll
    for (int q = 0; q < 2; ++q)
#pragma unroll
      for (int r = 0; r < 4; ++r) {
        int cc = rt * 16 + qrow * 4 + r;
        int hid = w * 32 + q * 16 + ln;
        out[(long)(cg * 32 + cc) * 512 + d * 256 + hid] = h_st[rt][q][r];
      }
}

extern "C" void kernel_launch(void* const* d_in, const int* in_sizes, int n_in,
                              void* d_out, int out_size, void* d_ws, size_t ws_size,
                              hipStream_t stream) {
  const float* emb  = (const float*)d_in[0];
  const float* wihf = (const float*)d_in[1];
  const float* whhf = (const float*)d_in[2];
  const float* bihf = (const float*)d_in[3];
  const float* bhhf = (const float*)d_in[4];
  const float* wihb = (const float*)d_in[5];
  const float* whhb = (const float*)d_in[6];
  const float* bihb = (const float*)d_in[7];
  const float* bhhb = (const float*)d_in[8];
  const int*   seq  = (const int*)d_in[9];
  float* out = (float*)d_out;

  char* ws = (char*)d_ws;
  // ws layout (bytes): xg 134217728 | X 20971520 | Wih 1310720 | Whh3 1048576 | bias 8192
  ushort* xg   = (ushort*)(ws);
  ushort* X    = (ushort*)(ws + 134217728);
  ushort* Wih  = (ushort*)(ws + 155189248);
  ushort* Whh3 = (ushort*)(ws + 156499968);
  float*  bias = (float*)(ws + 157548544);

  prep_kernel<<<dim3(1024), dim3(256), 0, stream>>>(emb, wihf, whhf, bihf, bhhf,
                                                    wihb, whhb, bihb, bhhb, seq,
                                                    X, Wih, Whh3, bias);
  gemm_xg_kernel<<<dim3(512, 8), dim3(256), 0, stream>>>(X, Wih, bias, xg);
  lstm_kernel<<<dim3(256), dim3(512), 0, stream>>>(xg, Whh3, out);
}